// Round 1
// baseline (537.968 us; speedup 1.0000x reference)
//
#include <hip/hip_runtime.h>

#define BB 8
#define TT 4096
#define DD 768
#define MM (BB*TT)   // 32768

typedef _Float16 f16;
typedef _Float16 f16x8 __attribute__((ext_vector_type(8)));
typedef float f32x4 __attribute__((ext_vector_type(4)));

typedef __attribute__((address_space(1))) void void_g;
typedef __attribute__((address_space(3))) void void_l;

// async global->LDS, 16B per lane. LDS dest = wave-uniform base + lane*16.
__device__ __forceinline__ void gload16(const void* g, void* l) {
  __builtin_amdgcn_global_load_lds((void_g*)g, (void_l*)l, 16, 0, 0);
}

// ---------------- f32 -> f16 convert (for weight matrices) ----------------
__global__ void cvt_f32_f16(const float* __restrict__ in, f16* __restrict__ out, int n) {
  int i0 = (blockIdx.x * blockDim.x + threadIdx.x) * 8;
  int stride = gridDim.x * blockDim.x * 8;
  for (int i = i0; i < n; i += stride) {
    float4 a = *(const float4*)(in + i);
    float4 b = *(const float4*)(in + i + 4);
    f16x8 o;
    o[0] = (f16)a.x; o[1] = (f16)a.y; o[2] = (f16)a.z; o[3] = (f16)a.w;
    o[4] = (f16)b.x; o[5] = (f16)b.y; o[6] = (f16)b.z; o[7] = (f16)b.w;
    *(f16x8*)(out + i) = o;
  }
}

// ---------------- projection GEMM: C[m,n] = sum_k A[m,k]*W[n,k] + bias[n] --
// A: MMxDD f32 (converted to f16 during staging), W: DDxDD f16, C: MMxDD f16
__global__ __launch_bounds__(256)
void proj_gemm(const float* __restrict__ Af, const f16* __restrict__ W,
               const float* __restrict__ bias, f16* __restrict__ C) {
  __shared__ f16 As[128 * 32];
  __shared__ f16 Ws[128 * 32];
  const int m0 = blockIdx.x * 128;
  const int n0 = blockIdx.y * 128;
  const int t = threadIdx.x;
  const int lane = t & 63;
  const int w = t >> 6;
  const int wm = (w >> 1) * 64;
  const int wn = (w & 1) * 64;
  const int fr = lane & 15, fq = lane >> 4;

  f32x4 acc[4][4] = {};

  // staging element indices (tile is 128 rows x 32 cols, row-major linear LDS)
  const int e0 = t * 8;
  const int r0 = e0 >> 5, c0 = e0 & 31;
  const int e1 = (256 + t) * 8;
  const int r1 = e1 >> 5, c1 = e1 & 31;

  for (int ks = 0; ks < 24; ++ks) {
    const int k0 = ks * 32;
    // async stage W tile (f16, direct to LDS)
    gload16(W + (size_t)(n0 + r0) * DD + k0 + c0, &Ws[(w * 64) * 8]);
    gload16(W + (size_t)(n0 + r1) * DD + k0 + c1, &Ws[(256 + w * 64) * 8]);
    // reg-stage A tile with f32->f16 conversion
    const float* ga0 = Af + (size_t)(m0 + r0) * DD + k0 + c0;
    const float* ga1 = Af + (size_t)(m0 + r1) * DD + k0 + c1;
    float4 x0 = *(const float4*)ga0, x1 = *(const float4*)(ga0 + 4);
    float4 y0 = *(const float4*)ga1, y1 = *(const float4*)(ga1 + 4);
    f16x8 va, vb;
    va[0] = (f16)x0.x; va[1] = (f16)x0.y; va[2] = (f16)x0.z; va[3] = (f16)x0.w;
    va[4] = (f16)x1.x; va[5] = (f16)x1.y; va[6] = (f16)x1.z; va[7] = (f16)x1.w;
    vb[0] = (f16)y0.x; vb[1] = (f16)y0.y; vb[2] = (f16)y0.z; vb[3] = (f16)y0.w;
    vb[4] = (f16)y1.x; vb[5] = (f16)y1.y; vb[6] = (f16)y1.z; vb[7] = (f16)y1.w;
    *(f16x8*)&As[e0] = va;
    *(f16x8*)&As[e1] = vb;
    __syncthreads();

    f16x8 a[4], b[4];
#pragma unroll
    for (int i = 0; i < 4; ++i)
      a[i] = *(const f16x8*)&As[(wm + i * 16 + fr) * 32 + fq * 8];
#pragma unroll
    for (int j = 0; j < 4; ++j)
      b[j] = *(const f16x8*)&Ws[(wn + j * 16 + fr) * 32 + fq * 8];
#pragma unroll
    for (int i = 0; i < 4; ++i)
#pragma unroll
      for (int j = 0; j < 4; ++j)
        acc[i][j] = __builtin_amdgcn_mfma_f32_16x16x32_f16(a[i], b[j], acc[i][j], 0, 0, 0);
    __syncthreads();
  }

  // epilogue: C/D layout col=lane&15, row=(lane>>4)*4+reg
#pragma unroll
  for (int j = 0; j < 4; ++j) {
    const int col = n0 + wn + j * 16 + fr;
    const float bv = bias[col];
#pragma unroll
    for (int i = 0; i < 4; ++i) {
#pragma unroll
      for (int r = 0; r < 4; ++r) {
        const int row = m0 + wm + i * 16 + fq * 4 + r;
        C[(size_t)row * DD + col] = (f16)(acc[i][j][r] + bv);
      }
    }
  }
}

// ---------------- flash stats: per-row online softmax (m, Z) + diagonal ----
// Q,K: (B*T) x D f16.  wdiag[b*T + t] = softmax(scores[b,t,:])[t]
__global__ __launch_bounds__(256)
void attn_stats(const f16* __restrict__ Q, const f16* __restrict__ K,
                const int* __restrict__ mask, float* __restrict__ wdiag) {
  __shared__ f16 Ks[128 * 32];
  const int bid = blockIdx.x;      // 512 blocks
  const int b = bid >> 6;          // 64 q-tiles of 64 rows per batch
  const int qt = bid & 63;
  const int q0 = qt * 64;
  const int t = threadIdx.x, lane = t & 63, w = t >> 6;
  const int fr = lane & 15, fq = lane >> 4;
  const int wrow = w * 16;         // wave owns 16 q-rows x 128 k-cols
  const float scale = 0.03608439182435161f;  // 1/sqrt(768)
  const int kdiag = qt >> 1;       // k-tile (of 128) containing this block's diagonal

  float m_run[4], Zr[4], sdiag[4];
#pragma unroll
  for (int r = 0; r < 4; ++r) { m_run[r] = -1e30f; Zr[r] = 0.f; sdiag[r] = -1e30f; }

  // hoist Q fragments to registers: rows wrow+fr, all 24 k-chunks
  f16x8 qfrag[24];
  {
    const f16* qp = Q + (size_t)(b * TT + q0 + wrow + fr) * DD + fq * 8;
#pragma unroll
    for (int d2 = 0; d2 < 24; ++d2) qfrag[d2] = *(const f16x8*)(qp + d2 * 32);
  }

  // K stage addressing (tile 128x32): thread covers 2 chunks of 8 elems
  const int rk = t >> 2, ck = (t & 3) * 8;

  for (int kt = 0; kt < 32; ++kt) {
    f32x4 acc[8] = {};
    const int krow = b * TT + kt * 128;
#pragma unroll
    for (int d2 = 0; d2 < 24; ++d2) {
      const int k0 = d2 * 32;
      gload16(K + (size_t)(krow + rk) * DD + k0 + ck, &Ks[(w * 64) * 8]);
      gload16(K + (size_t)(krow + 64 + rk) * DD + k0 + ck, &Ks[(256 + w * 64) * 8]);
      __syncthreads();
#pragma unroll
      for (int cf = 0; cf < 8; ++cf) {
        f16x8 bf = *(const f16x8*)&Ks[(cf * 16 + fr) * 32 + fq * 8];
        acc[cf] = __builtin_amdgcn_mfma_f32_16x16x32_f16(qfrag[d2], bf, acc[cf], 0, 0, 0);
      }
      __syncthreads();
    }

    // online softmax update for this 128-col strip
    int mv[8];
#pragma unroll
    for (int cf = 0; cf < 8; ++cf) mv[cf] = mask[b * TT + kt * 128 + cf * 16 + fr];

#pragma unroll
    for (int r = 0; r < 4; ++r) {
      const int qrow = q0 + wrow + fq * 4 + r;
      float sv[8];
#pragma unroll
      for (int cf = 0; cf < 8; ++cf) {
        float s = acc[cf][r] * scale;
        s = mv[cf] ? s : -1e30f;
        sv[cf] = s;
        if (kt == kdiag && (kt * 128 + cf * 16 + fr) == qrow) sdiag[r] = s;
      }
      float tmax = sv[0];
#pragma unroll
      for (int cf = 1; cf < 8; ++cf) tmax = fmaxf(tmax, sv[cf]);
#pragma unroll
      for (int off = 1; off < 16; off <<= 1) tmax = fmaxf(tmax, __shfl_xor(tmax, off));
      const float mnew = fmaxf(m_run[r], tmax);
      float p = 0.f;
#pragma unroll
      for (int cf = 0; cf < 8; ++cf) p += __expf(sv[cf] - mnew);
#pragma unroll
      for (int off = 1; off < 16; off <<= 1) p += __shfl_xor(p, off);
      Zr[r] = Zr[r] * __expf(m_run[r] - mnew) + p;
      m_run[r] = mnew;
    }
  }

#pragma unroll
  for (int r = 0; r < 4; ++r) {
    if (fr == fq * 4 + r) {   // the lane that captured this row's diagonal
      const int qrow = q0 + wrow + fq * 4 + r;
      wdiag[b * TT + qrow] = __expf(sdiag[r] - m_run[r]) / Zr[r];
    }
  }
}

// ---------------- output ----------------
__global__ void zero_out(float* out, int n) {
  int i = blockIdx.x * 256 + threadIdx.x;
  if (i < n) out[i] = 0.f;
}

// out[b,d] = sum_t X[b,t,d] * wdiag[b,t]
__global__ __launch_bounds__(256)
void out_gemv(const float* __restrict__ X, const float* __restrict__ wdiag,
              float* __restrict__ out) {
  __shared__ float wsm[256];
  const int b = blockIdx.z;
  const int d = blockIdx.y * 256 + threadIdx.x;
  const int tbase = blockIdx.x * 256;
  wsm[threadIdx.x] = wdiag[b * TT + tbase + threadIdx.x];
  __syncthreads();
  float acc = 0.f;
  const float* xp = X + (size_t)(b * TT + tbase) * DD + d;
#pragma unroll 4
  for (int i = 0; i < 256; ++i) acc += xp[(size_t)i * DD] * wsm[i];
  atomicAdd(&out[b * DD + d], acc);
}

extern "C" void kernel_launch(void* const* d_in, const int* in_sizes, int n_in,
                              void* d_out, int out_size, void* d_ws, size_t ws_size,
                              hipStream_t stream) {
  const float* X    = (const float*)d_in[0];
  const int*   mask = (const int*)d_in[1];
  const float* Wq_w = (const float*)d_in[2];
  const float* Wq_b = (const float*)d_in[3];
  const float* Wk_w = (const float*)d_in[4];
  const float* Wk_b = (const float*)d_in[5];
  float* out = (float*)d_out;

  // workspace layout (~103 MB)
  f16* Qh  = (f16*)d_ws;
  f16* Kh  = Qh + (size_t)MM * DD;
  f16* Wqh = Kh + (size_t)MM * DD;
  f16* Wkh = Wqh + (size_t)DD * DD;
  float* wdiag = (float*)(Wkh + (size_t)DD * DD);

  cvt_f32_f16<<<288, 256, 0, stream>>>(Wq_w, Wqh, DD * DD);
  cvt_f32_f16<<<288, 256, 0, stream>>>(Wk_w, Wkh, DD * DD);

  proj_gemm<<<dim3(256, 6), 256, 0, stream>>>(X, Wqh, Wq_b, Qh);
  proj_gemm<<<dim3(256, 6), 256, 0, stream>>>(X, Wkh, Wk_b, Kh);

  attn_stats<<<512, 256, 0, stream>>>(Qh, Kh, mask, wdiag);

  zero_out<<<24, 256, 0, stream>>>(out, BB * DD);
  out_gemv<<<dim3(16, 3, 8), 256, 0, stream>>>(X, wdiag, out);
}